// Round 5
// baseline (303.337 us; speedup 1.0000x reference)
//
#include <hip/hip_runtime.h>
#include <math.h>

// LogPolar resample: data [32,3,512,512] f32 -> out [32,3,512,512] f32.
// R2: latency-bound (occ 16.5%, HBM 18%). R4: chunked over 8 XCD-pinned
// image groups -> FETCH 327->50MB, occ 42%, dur 173us; still latency-bound
// (HBM 11%, VALU 8.8%). R5: maximize memory-level parallelism — issue all
// 48 gathers (12 images x 4 taps) back-to-back into registers before any
// compute/store, so one wave has ~48 loads in flight instead of ~16.

constexpr int H_IN  = 512;
constexpr int W_IN  = 512;
constexpr int H_OUT = 512;
constexpr int W_OUT = 512;
constexpr int BC    = 32 * 3;          // batch * channels
constexpr int IMG   = H_IN * W_IN;     // elements per image plane
constexpr int NPIX  = H_OUT * W_OUT;
constexpr int NCHUNK = 8;              // = #XCDs
constexpr int IMGS_PER_CHUNK = BC / NCHUNK;  // 12

__global__ __launch_bounds__(256) void logpolar_kernel(
    const float* __restrict__ data, float* __restrict__ out)
{
    // chunk pinned to XCD: consecutive blocks round-robin XCDs, so
    // blockIdx.x & 7 keeps one image-chunk's gathers in one L2.
    const int chunk  = blockIdx.x & (NCHUNK - 1);
    const int pixblk = blockIdx.x >> 3;
    const int pix = pixblk * blockDim.x + threadIdx.x;  // 0..262143
    if (pix >= NPIX) return;
    const int i = pix >> 9;            // theta index (output row)
    const int j = pix & (W_OUT - 1);   // r index (output col)

    // max_r = np.float32(log(norm([512,512])/2 * 2.0)) — f64 value, exact cast.
    const float max_r = (float)6.584898215319481;

    // Mirror reference f32 op order: (theta*2*pi)/H_OUT ; (r*max_r)/W_OUT
    const float theta  = ((float)(2 * i) * 3.14159274101257324f) / (float)H_OUT;
    const float radius = expf(((float)j * max_r) / (float)W_OUT);
    const float X = 256.0f + radius * cosf(theta);   // center_x + X0
    const float Y = 256.0f - radius * sinf(theta);   // center_y - Y0

    const float* p = data + (size_t)chunk * IMGS_PER_CHUNK * IMG;
    float*       q = out  + (size_t)chunk * IMGS_PER_CHUNK * IMG + pix;

    const bool in_bounds =
        (X >= 0.0f) && (X < (float)H_IN) && (Y >= 0.0f) && (Y < (float)W_IN);

    if (!in_bounds) {
        // mask == 0: reference multiplies the blend by 0 (inputs finite) -> exact 0.
        #pragma unroll
        for (int bc = 0; bc < IMGS_PER_CHUNK; ++bc) {
            q[bc * IMG] = 0.0f;
        }
        return;
    }

    // trunc-toward-zero (X,Y >= 0 here); in-bounds => already within [0,511].
    const int y_down = (int)Y;
    const int x_down = (int)X;
    const int y_up = min(y_down + 1, H_IN - 1);
    const int x_up = min(x_down + 1, W_IN - 1);

    const float yd = Y - (float)y_down;
    const float yu = Y - (float)y_up;
    const float xd = X - (float)x_down;
    const float xu = X - (float)x_up;

    const float dd = yd * yd + xd * xd;
    const float du = yd * yd + xu * xu;
    const float ud = yu * yu + xd * xd;
    const float uu = yu * yu + xu * xu;
    const float total = ((dd + du) + ud) + uu;

    const float wdd = dd / total;
    const float wdu = du / total;
    const float wud = ud / total;
    const float wuu = uu / total;

    const int o_dd = y_down * W_IN + x_down;
    const int o_du = y_down * W_IN + x_up;
    const int o_ud = y_up * W_IN + x_down;
    const int o_uu = y_up * W_IN + x_up;

    // ---- load phase: all 48 gathers issued before any use (full MLP) ----
    float g0[IMGS_PER_CHUNK], g1[IMGS_PER_CHUNK], g2[IMGS_PER_CHUNK], g3[IMGS_PER_CHUNK];
    #pragma unroll
    for (int bc = 0; bc < IMGS_PER_CHUNK; ++bc) {
        const float* pp = p + bc * IMG;
        g0[bc] = pp[o_dd];
        g1[bc] = pp[o_du];
        g2[bc] = pp[o_ud];
        g3[bc] = pp[o_uu];
    }

    // ---- compute + store phase ----
    #pragma unroll
    for (int bc = 0; bc < IMGS_PER_CHUNK; ++bc) {
        q[bc * IMG] = ((wdd * g0[bc] + wdu * g1[bc]) + wud * g2[bc]) + wuu * g3[bc];
    }
}

extern "C" void kernel_launch(void* const* d_in, const int* in_sizes, int n_in,
                              void* d_out, int out_size, void* d_ws, size_t ws_size,
                              hipStream_t stream)
{
    const float* data = (const float*)d_in[0];
    float* out = (float*)d_out;

    const int threads = 256;
    const int blocks = (NPIX / threads) * NCHUNK;  // 1024 * 8 = 8192
    logpolar_kernel<<<blocks, threads, 0, stream>>>(data, out);
}

// Round 6
// 242.523 us; speedup vs baseline: 1.2508x; 1.2508x over previous
//
#include <hip/hip_runtime.h>
#include <math.h>

// LogPolar resample: data [32,3,512,512] f32 -> out [32,3,512,512] f32.
// R2: latency-bound (occ 16.5%, HBM 18%), FETCH 327MB. R4: 8 XCD-pinned image
// chunks -> FETCH 50MB, 173us. R5: full-MLP batching regressed (190us) =>
// NOT latency-bound; bound on TA gather-transaction throughput (~1 txn per
// distinct 64B line per wave instr; model ~160us matches). R6: cut txns:
//  (a) float2 row-pair loads: taps (y,x),(y,x+1) in ONE 8B load (2x fewer
//      gather instrs + txns);
//  (b) 8x8-per-wave output tiles: input footprint per wave instr shrinks /
//      becomes rotation-invariant (fewer distinct lines than a 1x64 strip).

constexpr int H_IN  = 512;
constexpr int W_IN  = 512;
constexpr int H_OUT = 512;
constexpr int W_OUT = 512;
constexpr int BC    = 32 * 3;          // batch * channels
constexpr int IMG   = H_IN * W_IN;     // elements per image plane
constexpr int NCHUNK = 8;              // = #XCDs
constexpr int IPC   = BC / NCHUNK;     // 12 images per chunk

__device__ __forceinline__ float2 ld2(const float* p) {
    // well-defined unaligned 8B load; lowers to global_load_dwordx2 align 4
    float2 v;
    __builtin_memcpy(&v, p, sizeof(v));
    return v;
}

__global__ __launch_bounds__(256) void logpolar_kernel(
    const float* __restrict__ data, float* __restrict__ out)
{
    // chunk pinned to XCD: consecutive blocks round-robin the 8 XCDs.
    const int chunk = blockIdx.x & (NCHUNK - 1);
    const int tile  = blockIdx.x >> 3;            // 0..1023: 32x32 tiles of 16x16 px
    const int tile_i = (tile >> 5) << 4;
    const int tile_j = (tile & 31) << 4;

    // 8x8 px per wave; block = 2x2 waves = 16x16 px tile.
    const int t = threadIdx.x;
    const int w = t >> 6;                          // wave 0..3
    const int l = t & 63;                          // lane
    const int i = tile_i + ((w >> 1) << 3) + (l >> 3);   // theta row
    const int j = tile_j + ((w & 1) << 3) + (l & 7);     // r col
    const int pix = (i << 9) | j;

    // max_r = np.float32(log(norm([512,512])/2 * 2.0)) — f64 value, exact cast.
    const float max_r = (float)6.584898215319481;

    // Mirror reference f32 op order: (theta*2*pi)/H_OUT ; (r*max_r)/W_OUT
    const float theta  = ((float)(2 * i) * 3.14159274101257324f) / (float)H_OUT;
    const float radius = expf(((float)j * max_r) / (float)W_OUT);
    const float X = 256.0f + radius * cosf(theta);   // center_x + X0
    const float Y = 256.0f - radius * sinf(theta);   // center_y - Y0

    const float* p = data + (size_t)chunk * IPC * IMG;
    float*       q = out  + (size_t)chunk * IPC * IMG + pix;

    const bool in_bounds =
        (X >= 0.0f) && (X < (float)H_IN) && (Y >= 0.0f) && (Y < (float)W_IN);

    if (!in_bounds) {
        // mask == 0: reference multiplies the blend by 0 (inputs finite) -> exact 0.
        #pragma unroll
        for (int bc = 0; bc < IPC; ++bc) q[bc * IMG] = 0.0f;
        return;
    }

    // trunc-toward-zero (X,Y >= 0 here); in-bounds => within [0,511].
    const int y_down = (int)Y;
    const int x_down = (int)X;
    const int y_up = min(y_down + 1, H_IN - 1);
    const int x_up = min(x_down + 1, W_IN - 1);

    const float yd = Y - (float)y_down;
    const float yu = Y - (float)y_up;
    const float xd = X - (float)x_down;
    const float xu = X - (float)x_up;

    const float dd = yd * yd + xd * xd;
    const float du = yd * yd + xu * xu;
    const float ud = yu * yu + xd * xd;
    const float uu = yu * yu + xu * xu;
    const float total = ((dd + du) + ud) + uu;

    const float wdd = dd / total;
    const float wdu = du / total;
    const float wud = ud / total;
    const float wuu = uu / total;

    const int o_d = y_down * W_IN + x_down;   // row y_down, cols x_down..x_down+1
    const int o_u = y_up   * W_IN + x_down;   // row y_up

    if (x_down < W_IN - 1) {
        // common path: x_up == x_down+1 -> one float2 per row covers both taps
        #pragma unroll 4
        for (int bc = 0; bc < IPC; ++bc) {
            const float* pp = p + bc * IMG;
            const float2 a = ld2(pp + o_d);   // g_dd, g_du
            const float2 b = ld2(pp + o_u);   // g_ud, g_uu
            q[bc * IMG] = ((wdd * a.x + wdu * a.y) + wud * b.x) + wuu * b.y;
        }
    } else {
        // x_down == 511 -> x_up clamps to 511: both column taps alias
        #pragma unroll 4
        for (int bc = 0; bc < IPC; ++bc) {
            const float* pp = p + bc * IMG;
            const float ga = pp[o_d];
            const float gb = pp[o_u];
            q[bc * IMG] = ((wdd * ga + wdu * ga) + wud * gb) + wuu * gb;
        }
    }
}

extern "C" void kernel_launch(void* const* d_in, const int* in_sizes, int n_in,
                              void* d_out, int out_size, void* d_ws, size_t ws_size,
                              hipStream_t stream)
{
    const float* data = (const float*)d_in[0];
    float* out = (float*)d_out;

    const int threads = 256;                       // 16x16 px tile per block
    const int blocks = (H_OUT / 16) * (W_OUT / 16) * NCHUNK;  // 1024 * 8 = 8192
    logpolar_kernel<<<blocks, threads, 0, stream>>>(data, out);
}

// Round 8
// 236.382 us; speedup vs baseline: 1.2832x; 1.0260x over previous
//
#include <hip/hip_runtime.h>
#include <math.h>

// LogPolar resample: data [32,3,512,512] f32 -> out [32,3,512,512] f32.
// R4: 8 XCD-pinned image chunks -> FETCH 327->50MB, 173us.
// R6: float2 row-pair gathers + 8x8 wave tiles -> 113us (txn cut 2x -> 1.53x).
// R7: counters (HBM 20%, VALU 11%, occ 55%) say still gather-bound with
// exposed latency: unroll-4 loop drains vmcnt(0) every 4 images, MLP<=8.
// Fix: explicit 3-stage pipeline over image pairs (named buffers A/B/C),
// steady-state >=16 loads outstanding, plus nontemporal stores so the
// write stream doesn't pollute L1 (gathers are the only reuse).

constexpr int H_IN  = 512;
constexpr int W_IN  = 512;
constexpr int H_OUT = 512;
constexpr int W_OUT = 512;
constexpr int BC    = 32 * 3;          // batch * channels
constexpr int IMG   = H_IN * W_IN;     // elements per image plane
constexpr int NCHUNK = 8;              // = #XCDs
constexpr int IPC   = BC / NCHUNK;     // 12 images per chunk

__device__ __forceinline__ float2 ld2(const float* p) {
    // well-defined unaligned 8B load; lowers to global_load_dwordx2 align 4
    float2 v;
    __builtin_memcpy(&v, p, sizeof(v));
    return v;
}

__global__ __launch_bounds__(256) void logpolar_kernel(
    const float* __restrict__ data, float* __restrict__ out)
{
    // chunk pinned to XCD: consecutive blocks round-robin the 8 XCDs.
    const int chunk = blockIdx.x & (NCHUNK - 1);
    const int tile  = blockIdx.x >> 3;            // 0..1023: 32x32 tiles of 16x16 px
    const int tile_i = (tile >> 5) << 4;
    const int tile_j = (tile & 31) << 4;

    // 8x8 px per wave; block = 2x2 waves = 16x16 px tile.
    const int t = threadIdx.x;
    const int w = t >> 6;                          // wave 0..3
    const int l = t & 63;                          // lane
    const int i = tile_i + ((w >> 1) << 3) + (l >> 3);   // theta row
    const int j = tile_j + ((w & 1) << 3) + (l & 7);     // r col
    const int pix = (i << 9) | j;

    // max_r = np.float32(log(norm([512,512])/2 * 2.0)) — f64 value, exact cast.
    const float max_r = (float)6.584898215319481;

    // Mirror reference f32 op order: (theta*2*pi)/H_OUT ; (r*max_r)/W_OUT
    const float theta  = ((float)(2 * i) * 3.14159274101257324f) / (float)H_OUT;
    const float radius = expf(((float)j * max_r) / (float)W_OUT);
    const float X = 256.0f + radius * cosf(theta);   // center_x + X0
    const float Y = 256.0f - radius * sinf(theta);   // center_y - Y0

    const float* p = data + (size_t)chunk * IPC * IMG;
    float*       q = out  + (size_t)chunk * IPC * IMG + pix;

    const bool in_bounds =
        (X >= 0.0f) && (X < (float)H_IN) && (Y >= 0.0f) && (Y < (float)W_IN);

    if (!in_bounds) {
        // mask == 0: reference multiplies the blend by 0 (inputs finite) -> exact 0.
        #pragma unroll
        for (int bc = 0; bc < IPC; ++bc)
            __builtin_nontemporal_store(0.0f, q + bc * IMG);
        return;
    }

    // trunc-toward-zero (X,Y >= 0 here); in-bounds => within [0,511].
    const int y_down = (int)Y;
    const int x_down = (int)X;
    const int y_up = min(y_down + 1, H_IN - 1);
    const int x_up = min(x_down + 1, W_IN - 1);

    const float yd = Y - (float)y_down;
    const float yu = Y - (float)y_up;
    const float xd = X - (float)x_down;
    const float xu = X - (float)x_up;

    const float dd = yd * yd + xd * xd;
    const float du = yd * yd + xu * xu;
    const float ud = yu * yu + xd * xd;
    const float uu = yu * yu + xu * xu;
    const float total = ((dd + du) + ud) + uu;

    const float wdd = dd / total;
    const float wdu = du / total;
    const float wud = ud / total;
    const float wuu = uu / total;

    const int o_d = y_down * W_IN + x_down;   // row y_down, cols x_down..x_down+1
    const int o_u = y_up   * W_IN + x_down;   // row y_up

#define BLEND(a, b) (((wdd * (a).x + wdu * (a).y) + wud * (b).x) + wuu * (b).y)
#define ST(k, v) __builtin_nontemporal_store((v), q + (k) * IMG)

    if (x_down < W_IN - 1) {
        // 3-stage pipeline, 2 images per stage: >=16 loads in flight steady.
        float2 Aa0 = ld2(p + 0 * IMG + o_d), Ab0 = ld2(p + 0 * IMG + o_u);
        float2 Aa1 = ld2(p + 1 * IMG + o_d), Ab1 = ld2(p + 1 * IMG + o_u);
        float2 Ba0 = ld2(p + 2 * IMG + o_d), Bb0 = ld2(p + 2 * IMG + o_u);
        float2 Ba1 = ld2(p + 3 * IMG + o_d), Bb1 = ld2(p + 3 * IMG + o_u);
        float2 Ca0 = ld2(p + 4 * IMG + o_d), Cb0 = ld2(p + 4 * IMG + o_u);
        float2 Ca1 = ld2(p + 5 * IMG + o_d), Cb1 = ld2(p + 5 * IMG + o_u);

        ST(0, BLEND(Aa0, Ab0));
        ST(1, BLEND(Aa1, Ab1));
        Aa0 = ld2(p + 6 * IMG + o_d); Ab0 = ld2(p + 6 * IMG + o_u);
        Aa1 = ld2(p + 7 * IMG + o_d); Ab1 = ld2(p + 7 * IMG + o_u);

        ST(2, BLEND(Ba0, Bb0));
        ST(3, BLEND(Ba1, Bb1));
        Ba0 = ld2(p + 8 * IMG + o_d); Bb0 = ld2(p + 8 * IMG + o_u);
        Ba1 = ld2(p + 9 * IMG + o_d); Bb1 = ld2(p + 9 * IMG + o_u);

        ST(4, BLEND(Ca0, Cb0));
        ST(5, BLEND(Ca1, Cb1));
        Ca0 = ld2(p + 10 * IMG + o_d); Cb0 = ld2(p + 10 * IMG + o_u);
        Ca1 = ld2(p + 11 * IMG + o_d); Cb1 = ld2(p + 11 * IMG + o_u);

        ST(6, BLEND(Aa0, Ab0));
        ST(7, BLEND(Aa1, Ab1));
        ST(8, BLEND(Ba0, Bb0));
        ST(9, BLEND(Ba1, Bb1));
        ST(10, BLEND(Ca0, Cb0));
        ST(11, BLEND(Ca1, Cb1));
    } else {
        // x_down == 511 -> x_up clamps to 511: both column taps alias
        #pragma unroll
        for (int bc = 0; bc < IPC; ++bc) {
            const float* pp = p + bc * IMG;
            const float ga = pp[o_d];
            const float gb = pp[o_u];
            ST(bc, ((wdd * ga + wdu * ga) + wud * gb) + wuu * gb);
        }
    }
#undef BLEND
#undef ST
}

extern "C" void kernel_launch(void* const* d_in, const int* in_sizes, int n_in,
                              void* d_out, int out_size, void* d_ws, size_t ws_size,
                              hipStream_t stream)
{
    const float* data = (const float*)d_in[0];
    float* out = (float*)d_out;

    const int threads = 256;                       // 16x16 px tile per block
    const int blocks = (H_OUT / 16) * (W_OUT / 16) * NCHUNK;  // 1024 * 8 = 8192
    logpolar_kernel<<<blocks, threads, 0, stream>>>(data, out);
}